// Round 3
// baseline (179.969 us; speedup 1.0000x reference)
//
#include <hip/hip_runtime.h>
#include <hip/hip_cooperative_groups.h>

namespace cg = cooperative_groups;

#define DETN 128
#define NPIX (DETN * DETN)        // 16384 rays per projection
#define VDIM 128
#define NVOX (VDIM * VDIM * VDIM) // 2097152
#define NWORDS (NVOX / 32)        // 65536 words = 256 KiB per bit-volume
#define NSAMP 512
#define SPLITK 4
#define NBLK 256
#define NTHR (NBLK * 256)         // 65536 == NWORDS

// ---------------------------------------------------------------------------
// Ray task: identical math to the R2 bp_kernel (verified absmax 0.0).
//   frontal (view 0): z-packed  word = ix<<9 | iy<<2 | iz>>5, bit iz&31
//   lateral (view 1): x-packed  word = iz<<9 | iy<<2 | ix>>5, bit ix&31
// Run-merged bits -> one fire-and-forget atomicOr per ~13 samples.
// ---------------------------------------------------------------------------
__device__ __forceinline__ void do_ray(
    int p, int ray, int seg,
    const float* __restrict__ predF, const float* __restrict__ predL,
    const float* __restrict__ srcF,  const float* __restrict__ srcL,
    const float* __restrict__ tgtF,  const float* __restrict__ tgtL,
    const float* __restrict__ Ainv,  const float* __restrict__ tinv,
    unsigned int* __restrict__ flags)
{
    const int view  = p & 1;
    const int batch = p >> 1;

    const float* mask = (view ? predL : predF) + batch * NPIX;
    if (!(mask[ray] > 0.5f)) return;   // inactive ray

    const float* src = view ? srcL : srcF;
    const float* tgt = (view ? tgtL : tgtF) + ray * 3;

    const float sx = src[0], sy = src[1], sz = src[2];
    float dx = tgt[0] - sx, dy = tgt[1] - sy, dz = tgt[2] - sz;
    const float len = sqrtf(dx * dx + dy * dy + dz * dz);
    const float inv = 1.0f / (len + 1e-8f);
    dx *= inv; dy *= inv; dz *= inv;

    // voxel coords affine in t:  q(t) = qc + qd * t
    const float a00 = Ainv[0], a01 = Ainv[1], a02 = Ainv[2];
    const float a10 = Ainv[3], a11 = Ainv[4], a12 = Ainv[5];
    const float a20 = Ainv[6], a21 = Ainv[7], a22 = Ainv[8];
    const float qcx = a00 * sx + a01 * sy + a02 * sz + tinv[0];
    const float qcy = a10 * sx + a11 * sy + a12 * sz + tinv[1];
    const float qcz = a20 * sx + a21 * sy + a22 * sz + tinv[2];
    const float qdx = a00 * dx + a01 * dy + a02 * dz;
    const float qdy = a10 * dx + a11 * dy + a12 * dz;
    const float qdz = a20 * dx + a21 * dy + a22 * dz;

    const float tmax = len * 2.5f;
    const float dt   = tmax * (1.0f / 511.0f);   // t_k = k * dt

    // slab intersection (with margin) to skip out-of-bounds samples
    float tlo = 0.0f, thi = tmax;
    {
        const float c[3] = {qcx, qcy, qcz};
        const float d[3] = {qdx, qdy, qdz};
        #pragma unroll
        for (int j = 0; j < 3; ++j) {
            if (fabsf(d[j]) < 1e-8f) {
                if (c[j] < -0.6f || c[j] > 127.6f) thi = -1.0f;  // empty
            } else {
                const float ta = (-0.6f  - c[j]) / d[j];
                const float tb = (127.6f - c[j]) / d[j];
                tlo = fmaxf(tlo, fminf(ta, tb));
                thi = fminf(thi, fmaxf(ta, tb));
            }
        }
    }
    if (tlo > thi) return;
    const int klo = max(0, (int)ceilf(tlo / dt));
    const int khi = min(NSAMP - 1, (int)floorf(thi / dt));

    // this task's k-segment
    const int n   = khi - klo + 1;
    const int per = (n + SPLITK - 1) / SPLITK;
    const int k0  = klo + seg * per;
    const int k1  = min(khi, k0 + per - 1);
    if (k0 > khi) return;

    unsigned int* __restrict__ vol = flags + (size_t)p * NWORDS;
    int      curw = -1;
    unsigned bits = 0;
    for (int k = k0; k <= k1; ++k) {
        const float t  = (float)k * dt;
        const float qx = fmaf(qdx, t, qcx);
        const float qy = fmaf(qdy, t, qcy);
        const float qz = fmaf(qdz, t, qcz);
        const int ix = (int)rintf(qx);   // ties-to-even, matches jnp.round
        const int iy = (int)rintf(qy);
        const int iz = (int)rintf(qz);
        if ((unsigned)ix < (unsigned)VDIM && (unsigned)iy < (unsigned)VDIM &&
            (unsigned)iz < (unsigned)VDIM) {
            const int maj = view ? iz : ix;   // slow axis
            const int pk  = view ? ix : iz;   // packed (fast) axis
            const int w   = (maj << 9) | (iy << 2) | (pk >> 5);
            const unsigned bit = 1u << (pk & 31);
            if (w == curw) {
                bits |= bit;
            } else {
                if (curw >= 0) atomicOr(&vol[curw], bits);
                curw = w; bits = bit;
            }
        }
    }
    if (curw >= 0) atomicOr(&vol[curw], bits);
}

// ---------------------------------------------------------------------------
// Fused: zero -> backproject -> (inline transpose) loss. One dispatch.
// ---------------------------------------------------------------------------
__global__ __launch_bounds__(256) void fused_kernel(
    const float* __restrict__ predF, const float* __restrict__ predL,
    const float* __restrict__ srcF,  const float* __restrict__ srcL,
    const float* __restrict__ tgtF,  const float* __restrict__ tgtL,
    const float* __restrict__ gt,
    const float* __restrict__ Ainv,  const float* __restrict__ tinv,
    unsigned int* __restrict__ flags, float* __restrict__ out,
    int B, float scale)
{
    cg::grid_group grid = cg::this_grid();
    const int tid = blockIdx.x * blockDim.x + threadIdx.x;   // [0, NTHR)

    // ---- Phase A: zero bitmaps (2B * 256 KiB) + out ----
    {
        const int total4 = (2 * B * NWORDS) >> 2;            // uint4 count
        uint4* f4 = (uint4*)flags;
        const uint4 z = make_uint4(0u, 0u, 0u, 0u);
        for (int i = tid; i < total4; i += NTHR) f4[i] = z;
        if (tid == 0) *out = 0.0f;
    }
    grid.sync();

    // ---- Phase B: backprojection ----
    {
        const int ntask = 2 * B * NPIX * SPLITK;
        for (int t = tid; t < ntask; t += NTHR) {
            const int ray  = t & (NPIX - 1);
            const int rest = t >> 14;                        // NPIX = 1<<14
            const int p    = rest % (2 * B);
            const int seg  = rest / (2 * B);
            do_ray(p, ray, seg, predF, predL, srcF, srcL, tgtF, tgtL,
                   Ainv, tinv, flags);
        }
    }
    grid.sync();

    // ---- Phase C: loss (one z-packed word per thread; NTHR == NWORDS) ----
    float acc = 0.0f;
    {
        const int w = tid;
        const int x = w >> 9;
        const int y = (w >> 2) & 127;
        const int Z = w & 3;
        const int base = (y << 2) | (x >> 5);
        const int sh   = x & 31;

        const float4* __restrict__ g4 = (const float4*)(gt + (size_t)w * 32);
        float g[32];
        #pragma unroll
        for (int q = 0; q < 8; ++q) {
            const float4 v = g4[q];
            g[4 * q + 0] = v.x; g[4 * q + 1] = v.y;
            g[4 * q + 2] = v.z; g[4 * q + 3] = v.w;
        }

        for (int b = 0; b < B; ++b) {
            const unsigned F = flags[(size_t)(2 * b) * NWORDS + w];
            // inline bit-transpose gather of the x-packed lateral volume
            const unsigned int* __restrict__ sl =
                flags + (size_t)(2 * b + 1) * NWORDS;
            unsigned L = 0;
            #pragma unroll
            for (int zz = 0; zz < 32; ++zz) {
                L |= ((sl[(((Z << 5) + zz) << 9) | base] >> sh) & 1u) << zz;
            }
            const int n2 = __popc(F & L);
            const int n1 = __popc(F | L) - n2;
            const int n0 = 32 - n1 - n2;
            acc += 0.6931471806f * (float)n0 + 1.3132616875f * (float)n1 +
                   2.1269280110f * (float)n2;
            float s = 0.0f;
            #pragma unroll
            for (int i = 0; i < 32; ++i) {
                s += g[i] * (float)(((F >> i) & 1u) + ((L >> i) & 1u));
            }
            acc -= s;
        }
    }

    // wave reduce (64 lanes) then block reduce, one atomicAdd per block
    #pragma unroll
    for (int off = 32; off > 0; off >>= 1) acc += __shfl_down(acc, off);

    __shared__ float smem[4];   // 256 threads = 4 waves
    const int wid  = threadIdx.x >> 6;
    const int lane = threadIdx.x & 63;
    if (lane == 0) smem[wid] = acc;
    __syncthreads();
    if (threadIdx.x == 0) {
        const float tot = smem[0] + smem[1] + smem[2] + smem[3];
        atomicAdd(out, tot * scale);
    }
}

extern "C" void kernel_launch(void* const* d_in, const int* in_sizes, int n_in,
                              void* d_out, int out_size, void* d_ws, size_t ws_size,
                              hipStream_t stream) {
    const float* predF = (const float*)d_in[0];
    const float* predL = (const float*)d_in[1];
    const float* srcF  = (const float*)d_in[2];
    const float* tgtF  = (const float*)d_in[3];
    const float* srcL  = (const float*)d_in[4];
    const float* tgtL  = (const float*)d_in[5];
    const float* gt    = (const float*)d_in[6];
    const float* Ainv  = (const float*)d_in[7];
    const float* tinv  = (const float*)d_in[8];

    int B = in_sizes[0] / NPIX;                    // = 2
    unsigned int* flags = (unsigned int*)d_ws;     // 2B bit-volumes, 256 KiB each
    float* outp = (float*)d_out;
    float scale = 1.0f / ((float)NVOX * (float)B);

    void* args[] = {
        (void*)&predF, (void*)&predL, (void*)&srcF, (void*)&srcL,
        (void*)&tgtF,  (void*)&tgtL,  (void*)&gt,   (void*)&Ainv,
        (void*)&tinv,  (void*)&flags, (void*)&outp, (void*)&B, (void*)&scale
    };
    hipLaunchCooperativeKernel((void*)fused_kernel, dim3(NBLK), dim3(256),
                               args, 0, stream);
}